// Round 9
// baseline (315.811 us; speedup 1.0000x reference)
//
#include <hip/hip_runtime.h>

#define PFEAT 58
#define S18   18
#define ENT   324   // 18*18
#define MAXE  128   // max staged CSR entries per atom (avg degree ~32)
#define MAXA  256   // max atoms for in-prep CSR build

// p -> (row,col,factor) tables for _assemble (FLIST=[1,3,5], offs=[0,1,4])
__device__ __constant__ unsigned char c_row[PFEAT] = {
    0,0,0,0,0,0,0,0,0,
    1,1,1,2,2,2,3,3,3,
    1,1,1,1,1,2,2,2,2,2,3,3,3,3,3,
    4,4,4,4,4,5,5,5,5,5,6,6,6,6,6,7,7,7,7,7,8,8,8,8,8};
__device__ __constant__ unsigned char c_col[PFEAT] = {
    0,1,2,3,4,5,6,7,8,
    1,2,3,1,2,3,1,2,3,
    4,5,6,7,8,4,5,6,7,8,4,5,6,7,8,
    4,5,6,7,8,4,5,6,7,8,4,5,6,7,8,4,5,6,7,8,4,5,6,7,8};
__device__ __constant__ float c_fac[PFEAT] = {
    0.5f,1,1,1,1,1,1,1,1,
    0.5f,0.5f,0.5f,0.5f,0.5f,0.5f,0.5f,0.5f,0.5f,
    1,1,1,1,1,1,1,1,1,1,1,1,1,1,1,
    0.5f,0.5f,0.5f,0.5f,0.5f,0.5f,0.5f,0.5f,0.5f,0.5f,0.5f,0.5f,0.5f,
    0.5f,0.5f,0.5f,0.5f,0.5f,0.5f,0.5f,0.5f,0.5f,0.5f,0.5f,0.5f};

// int64-vs-int32 probe for edge_index (reference declares int64).
__device__ __forceinline__ bool detect_i64(const int* __restrict__ ei) {
    const uint2* p = (const uint2*)ei;
    unsigned acc = 0u;
#pragma unroll 8
    for (int m = 0; m < 64; ++m) acc |= p[m].y;
    return acc == 0u;
}

__device__ __forceinline__ int load_idx(const int* __restrict__ ei, int pos,
                                        bool is64, int A) {
    int v = is64 ? ei[2 * pos] : ei[pos];
    v = v < 0 ? 0 : (v >= A ? A - 1 : v);   // never fault on bad decode
    return v;
}

// Assemble 9x9 from feats, spin-double, rotate: sM = Rs * H18 * Rd^T.
__device__ __forceinline__ void assemble_rotate(
    const float* __restrict__ feat, const float* __restrict__ Rs,
    const float* __restrict__ Rd, float* sH9, float* sRs, float* sRd,
    float* sT, float* sM, int t, int nthreads)
{
    for (int idx = t; idx < ENT; idx += nthreads) { sRs[idx] = Rs[idx]; sRd[idx] = Rd[idx]; }
    if (t < 81) sH9[t] = 0.f;
    __syncthreads();
    if (t < PFEAT) sH9[c_row[t] * 9 + c_col[t]] = c_fac[t] * feat[t];
    __syncthreads();

    for (int idx = t; idx < ENT; idx += nthreads) {
        const int pp = idx / S18, q = idx - pp * S18;
        const int i = pp >> 1, u = pp & 1;
        float acc = 0.f;
#pragma unroll
        for (int j = 0; j < 9; ++j)
            acc += sH9[i * 9 + j] * sRd[q * S18 + 2 * j + u];
        sT[idx] = acc;
    }
    __syncthreads();

    for (int idx = t; idx < ENT; idx += nthreads) {
        const int p = idx / S18, q = idx - p * S18;
        float acc = 0.f;
#pragma unroll
        for (int pp = 0; pp < S18; ++pp)
            acc += sRs[p * S18 + pp] * sT[pp * S18 + q];
        sM[idx] = acc;
    }
}

// ---------------- CSR (write-once) path ----------------

// Block-specialized prep: blocks [0,E) edge rotate (+T, +phases);
// [E,E+A) onsite rotate; block E+A builds CSR. All independent.
__global__ __launch_bounds__(128) void prep_kernel(
    const float* __restrict__ hop_feat, const float* __restrict__ ons_feat,
    const float* __restrict__ R, const int* __restrict__ ei,
    const float* __restrict__ kpts, const float* __restrict__ shift,
    float* __restrict__ hop_rot, float* __restrict__ hop_rotT,
    float* __restrict__ ons_rot, float* __restrict__ pcos,
    float* __restrict__ psin, int* __restrict__ offsets,
    int2* __restrict__ entries, int E, int A, int K, int hasT)
{
    __shared__ float sH9[81];
    __shared__ float sRs[ENT];
    __shared__ float sRd[ENT];
    __shared__ float sT[ENT];
    __shared__ float sM[ENT];
    __shared__ int   scnt[MAXA];
    __shared__ int   scur[MAXA];
    __shared__ int   sflag;

    const int item = blockIdx.x;
    const int t = threadIdx.x;
    if (t == 0) sflag = detect_i64(ei) ? 1 : 0;
    __syncthreads();
    const bool s64 = sflag != 0;

    if (item == E + A) {
        // ---- CSR build ----
        for (int a = t; a < A; a += 128) scnt[a] = 0;
        __syncthreads();
        for (int e = t; e < E; e += 128) {
            const int a = load_idx(ei, e, s64, A);
            const int b = load_idx(ei, E + e, s64, A);
            atomicAdd(&scnt[a], 1);
            atomicAdd(&scnt[b], 1);
        }
        __syncthreads();
        if (t == 0) {
            int acc = 0;
            for (int a = 0; a < A; ++a) { scur[a] = acc; offsets[a] = acc; acc += scnt[a]; }
            offsets[A] = acc;
        }
        __syncthreads();
        for (int e = t; e < E; e += 128) {
            const int a = load_idx(ei, e, s64, A);
            const int b = load_idx(ei, E + e, s64, A);
            const int p = atomicAdd(&scur[a], 1);
            entries[p] = make_int2(e, b);                 // direct: row-atom a, col-block b
            const int q = atomicAdd(&scur[b], 1);
            entries[q] = make_int2(e | (1 << 30), a);     // conj:   row-atom b, col-block a
        }
        return;
    }

    const float* feat; const float* Rs; const float* Rd; float* outp;
    if (item < E) {
        const int a_s = load_idx(ei, item, s64, A);
        const int a_d = load_idx(ei, E + item, s64, A);
        feat = hop_feat + (size_t)item * PFEAT;
        Rs = R + (size_t)a_s * ENT;
        Rd = R + (size_t)a_d * ENT;
        outp = hop_rot + (size_t)item * ENT;
        for (int k = t; k < K; k += 128) {
            const float dot = kpts[k * 3 + 0] * shift[3 * item + 0]
                            + kpts[k * 3 + 1] * shift[3 * item + 1]
                            + kpts[k * 3 + 2] * shift[3 * item + 2];
            float sv, cv;
            sincosf(-6.28318530717958647692f * dot, &sv, &cv);
            pcos[item * K + k] = cv;
            psin[item * K + k] = sv;
        }
    } else {
        const int a = item - E;
        feat = ons_feat + (size_t)a * PFEAT;
        Rs = R + (size_t)a * ENT;
        Rd = Rs;
        outp = ons_rot + (size_t)a * ENT;
    }

    assemble_rotate(feat, Rs, Rd, sH9, sRs, sRd, sT, sM, t, 128);
    __syncthreads();

    for (int idx = t; idx < ENT; idx += 128) outp[idx] = sM[idx];
    if (item < E && hasT) {
        float* outpT = hop_rotT + (size_t)item * ENT;
        for (int idx = t; idx < ENT; idx += 128) {
            const int p = idx / S18, q = idx - p * S18;
            outpT[idx] = sM[q * S18 + p];   // T[p][q] = M[q][p]
        }
    }
}

// K-fused column-owner register writer (real mode, K<=4). One block per
// (col-chunk, atom-row a). Thread owns column c, accumulates 18 rows x K
// planes in VGPRs; each matching entry's 18-float gather is loaded ONCE
// and fed to all K planes. 18*K coalesced row stores. One barrier.
__global__ __launch_bounds__(256) void writer_colsK_kernel(
    const float* __restrict__ hop_rot,    // [E,324]
    const float* __restrict__ hop_rotT,   // [E,324]
    const float* __restrict__ ons_rot,    // [A,324]
    const int*   __restrict__ offsets,    // [A+1]
    const int2*  __restrict__ entries,    // [2E]
    const float* __restrict__ pcos,       // [E,K]
    float* __restrict__ outf,
    int A, int K, long long lim)
{
    __shared__ int   se[MAXE];
    __shared__ int   sb[MAXE];
    __shared__ float spc[MAXE][4];
    __shared__ float sons[ENT];

    const int N = A * S18;
    const long long N2 = (long long)N * N;
    const int a = blockIdx.y;
    const int t = threadIdx.x;
    const int c = blockIdx.x * 256 + t;

    const int beg = offsets[a];
    const int cnt = offsets[a + 1] - beg;
    const int nst = cnt < MAXE ? cnt : MAXE;
    for (int n = t; n < nst; n += 256) {
        const int2 ent = entries[beg + n];
        se[n] = ent.x;
        sb[n] = ent.y;
        const int e0 = ent.x & 0x3FFFFFFF;
        for (int k = 0; k < K; ++k) spc[n][k] = pcos[e0 * K + k];
    }
    for (int idx = t; idx < ENT; idx += 256) sons[idx] = ons_rot[a * ENT + idx];
    __syncthreads();

    if (c >= N) return;
    const int b = c / S18, l = c - b * S18;

    float acc[4][S18];
#pragma unroll
    for (int k = 0; k < 4; ++k)
#pragma unroll
        for (int i = 0; i < S18; ++i) acc[k][i] = 0.f;

    if (b == a) {
#pragma unroll
        for (int i = 0; i < S18; ++i) {
            const float v = sons[i * S18 + l] + sons[l * S18 + i];
            for (int k = 0; k < K; ++k) acc[k][i] = v;
        }
    }

    for (int n = 0; n < nst; ++n) {
        if (sb[n] != b) continue;
        const int ex = se[n];
        const int e = ex & 0x3FFFFFFF;
        // direct: need col l of M (= row l of M^T); conj: need row l of M.
        const float* base = ((ex >> 30) & 1)
                          ? (hop_rot  + (size_t)e * ENT + l * S18)
                          : (hop_rotT + (size_t)e * ENT + l * S18);
        float v[S18];
#pragma unroll
        for (int i = 0; i < S18; ++i) v[i] = base[i];
        for (int k = 0; k < K; ++k) {
            const float pc = spc[n][k];
#pragma unroll
            for (int i = 0; i < S18; ++i) acc[k][i] += v[i] * pc;
        }
    }
    for (int n = MAXE; n < cnt; ++n) {       // overflow path (rare)
        const int2 ent = entries[beg + n];
        if (ent.y != b) continue;
        const int e = ent.x & 0x3FFFFFFF;
        const float* base = ((ent.x >> 30) & 1)
                          ? (hop_rot  + (size_t)e * ENT + l * S18)
                          : (hop_rotT + (size_t)e * ENT + l * S18);
        float v[S18];
#pragma unroll
        for (int i = 0; i < S18; ++i) v[i] = base[i];
        for (int k = 0; k < K; ++k) {
            const float pc = pcos[e * K + k];
#pragma unroll
            for (int i = 0; i < S18; ++i) acc[k][i] += v[i] * pc;
        }
    }

    const long long colbase = (long long)a * S18 * N + c;
    for (int k = 0; k < K; ++k) {
        const long long kb = (long long)k * N2 + colbase;
#pragma unroll
        for (int i = 0; i < S18; ++i) {
            const long long off = kb + (long long)i * N;
            if (off < lim) outf[off] = acc[k][i];
        }
    }
}

// Per-k column-owner writer (real mode, any K) — R8 version.
__global__ __launch_bounds__(384) void writer_cols_kernel(
    const float* __restrict__ hop_rot, const float* __restrict__ hop_rotT,
    const float* __restrict__ ons_rot, const int* __restrict__ offsets,
    const int2* __restrict__ entries, const float* __restrict__ pcos,
    float* __restrict__ outf, int A, int K, long long lim)
{
    __shared__ int   se[MAXE];
    __shared__ int   sb[MAXE];
    __shared__ float spc[MAXE];
    __shared__ float sons[ENT];

    const int N = A * S18;
    const int a = blockIdx.z;
    const int k = blockIdx.y;
    const int t = threadIdx.x;
    const int c = blockIdx.x * 384 + t;

    const int beg = offsets[a];
    const int cnt = offsets[a + 1] - beg;
    const int nst = cnt < MAXE ? cnt : MAXE;
    for (int n = t; n < nst; n += 384) {
        const int2 ent = entries[beg + n];
        se[n] = ent.x;
        sb[n] = ent.y;
        spc[n] = pcos[(ent.x & 0x3FFFFFFF) * K + k];
    }
    for (int idx = t; idx < ENT; idx += 384) sons[idx] = ons_rot[a * ENT + idx];
    __syncthreads();

    if (c >= N) return;
    const int b = c / S18, l = c - b * S18;

    float acc[S18];
    if (b == a) {
#pragma unroll
        for (int i = 0; i < S18; ++i)
            acc[i] = sons[i * S18 + l] + sons[l * S18 + i];
    } else {
#pragma unroll
        for (int i = 0; i < S18; ++i) acc[i] = 0.f;
    }

    for (int n = 0; n < nst; ++n) {
        if (sb[n] != b) continue;
        const int ex = se[n];
        const int e = ex & 0x3FFFFFFF;
        const float pc = spc[n];
        const float* base = ((ex >> 30) & 1)
                          ? (hop_rot  + (size_t)e * ENT + l * S18)
                          : (hop_rotT + (size_t)e * ENT + l * S18);
#pragma unroll
        for (int i = 0; i < S18; ++i) acc[i] += base[i] * pc;
    }
    for (int n = MAXE; n < cnt; ++n) {
        const int2 ent = entries[beg + n];
        if (ent.y != b) continue;
        const int e = ent.x & 0x3FFFFFFF;
        const float pc = pcos[e * K + k];
        const float* base = ((ent.x >> 30) & 1)
                          ? (hop_rot  + (size_t)e * ENT + l * S18)
                          : (hop_rotT + (size_t)e * ENT + l * S18);
#pragma unroll
        for (int i = 0; i < S18; ++i) acc[i] += base[i] * pc;
    }

    const long long rowbase = ((long long)k * N + (long long)a * S18) * (long long)N + c;
#pragma unroll
    for (int i = 0; i < S18; ++i) {
        const long long off = rowbase + (long long)i * N;
        if (off < lim) outf[off] = acc[i];
    }
}

// General writer (handles cplx) — LDS rowbuf version, fallback only.
__global__ __launch_bounds__(256) void write_kernel(
    const float* __restrict__ hop_rot, const float* __restrict__ hop_rotT,
    const float* __restrict__ ons_rot, const int* __restrict__ offsets,
    const int2* __restrict__ entries, const float* __restrict__ pcos,
    const float* __restrict__ psin, float* __restrict__ outf,
    int A, int K, int cplx, int hasT, long long lim)
{
    extern __shared__ float rowbuf[];     // (cplx?2:1)*N floats
    __shared__ int2  sent[MAXE];
    __shared__ float sphc[MAXE];
    __shared__ float sphs[MAXE];
    __shared__ float sons[ENT];

    const int N = A * S18;
    const int a    = blockIdx.x >> 1;
    const int half = blockIdx.x & 1;
    const int k = blockIdx.y;
    const int t = threadIdx.x;
    const int i0 = half * 9;
    const int stride = cplx ? 2 : 1;
    const int nbuf = stride * N;
    const int nbuf4 = nbuf >> 2;

    const int beg = offsets[a], end = offsets[a + 1];
    const int cnt = end - beg;
    const int nst = cnt < MAXE ? cnt : MAXE;
    for (int n = t; n < nst; n += 256) {
        const int2 ent = entries[beg + n];
        sent[n] = ent;
        const int e0 = ent.x & 0x3FFFFFFF;
        sphc[n] = pcos[e0 * K + k];
        if (cplx) sphs[n] = psin[e0 * K + k];
    }
    for (int idx = t; idx < ENT; idx += 256) sons[idx] = ons_rot[a * ENT + idx];
    __syncthreads();

    float4* rb4 = (float4*)rowbuf;
    const int total = cnt * S18;

    for (int ri = 0; ri < 9; ++ri) {
        const int i = i0 + ri;
        for (int idx = t; idx < nbuf4; idx += 256)
            rb4[idx] = make_float4(0.f, 0.f, 0.f, 0.f);
        __syncthreads();

        if (t < S18)
            atomicAdd(&rowbuf[stride * (a * S18 + t)],
                      sons[i * S18 + t] + sons[t * S18 + i]);

        for (int m = t; m < total; m += 256) {
            const int n = m / S18, l = m - n * S18;
            int2 ent; float pc, ps = 0.f;
            if (n < MAXE) {
                ent = sent[n]; pc = sphc[n]; if (cplx) ps = sphs[n];
            } else {
                ent = entries[beg + n];
                const int e0 = ent.x & 0x3FFFFFFF;
                pc = pcos[e0 * K + k]; if (cplx) ps = psin[e0 * K + k];
            }
            const int conjf = (ent.x >> 30) & 1;
            const int e = ent.x & 0x3FFFFFFF;
            const int b = ent.y;
            float v;
            if (!conjf)     v = hop_rot [(size_t)e * ENT + i * S18 + l];
            else if (hasT)  v = hop_rotT[(size_t)e * ENT + i * S18 + l];
            else            v = hop_rot [(size_t)e * ENT + l * S18 + i];
            atomicAdd(&rowbuf[stride * (b * S18 + l)], v * pc);
            if (cplx)
                atomicAdd(&rowbuf[stride * (b * S18 + l) + 1], conjf ? -v * ps : v * ps);
        }
        __syncthreads();

        const long long base = (long long)stride
                             * ((long long)k * N + (long long)a * S18 + i)
                             * (long long)N;
        float* dst = outf + base;
        if (base + nbuf <= lim && ((base & 3) == 0)) {
            float4* d4 = (float4*)dst;
            for (int idx = t; idx < nbuf4; idx += 256) d4[idx] = rb4[idx];
        } else {
            for (int idx = t; idx < nbuf; idx += 256)
                if (base + idx < lim) dst[idx] = rowbuf[idx];
        }
        __syncthreads();
    }
}

// ---------------- fallback (R3 atomic) path ----------------

__global__ __launch_bounds__(256) void zero_kernel(float* __restrict__ p, long long n)
{
    const long long i4 = ((long long)blockIdx.x * 256 + threadIdx.x) * 4;
    if (i4 + 3 < n) {
        *(float4*)(p + i4) = make_float4(0.f, 0.f, 0.f, 0.f);
    } else if (i4 < n) {
        for (long long i = i4; i < n; ++i) p[i] = 0.f;
    }
}

__global__ __launch_bounds__(256) void edge_kernel(
    const float* __restrict__ hop_feat, const float* __restrict__ R,
    const float* __restrict__ kpts, const float* __restrict__ shift,
    const int* __restrict__ edge_index, float* __restrict__ outf,
    int E, int A, int K, int cplx, long long lim)
{
    __shared__ float sH9[81];
    __shared__ float sRs[ENT];
    __shared__ float sRd[ENT];
    __shared__ float sT[ENT];
    __shared__ float sM[ENT];
    __shared__ float sC[8];
    __shared__ float sS[8];

    const int e = blockIdx.x;
    const int t = threadIdx.x;
    const int N = A * S18;
    const long long N2 = (long long)N * N;

    const bool is64 = detect_i64(edge_index);
    const int a = load_idx(edge_index, e, is64, A);
    const int b = load_idx(edge_index, E + e, is64, A);

    if (t < K && t < 8) {
        const float sx = shift[e * 3 + 0], sy = shift[e * 3 + 1], sz = shift[e * 3 + 2];
        const float dot = kpts[t * 3 + 0] * sx + kpts[t * 3 + 1] * sy + kpts[t * 3 + 2] * sz;
        float sv, cv;
        sincosf(-6.28318530717958647692f * dot, &sv, &cv);
        sC[t] = cv; sS[t] = sv;
    }

    assemble_rotate(hop_feat + (size_t)e * PFEAT,
                    R + (size_t)a * ENT, R + (size_t)b * ENT,
                    sH9, sRs, sRd, sT, sM, t, 256);
    __syncthreads();

    const int total = K * ENT;
    for (int idx = t; idx < total; idx += 256) {
        const int k = idx / ENT, r = idx - k * ENT;
        const int i = r / S18, j = r - i * S18;
        const float v = sM[r];
        const float re = v * sC[k];
        const float im = v * sS[k];
        const long long I = (long long)a * S18 + i;
        const long long J = (long long)b * S18 + j;
        const long long p1 = k * N2 + I * N + J;
        const long long p2 = k * N2 + J * N + I;
        if (cplx) {
            if (2 * p1 + 1 < lim) { atomicAdd(&outf[2 * p1], re); atomicAdd(&outf[2 * p1 + 1], im); }
            if (2 * p2 + 1 < lim) { atomicAdd(&outf[2 * p2], re); atomicAdd(&outf[2 * p2 + 1], -im); }
        } else {
            if (p1 < lim) atomicAdd(&outf[p1], re);
            if (p2 < lim) atomicAdd(&outf[p2], re);
        }
    }
}

__global__ __launch_bounds__(128) void onsite_kernel(
    const float* __restrict__ ons_feat, const float* __restrict__ R,
    float* __restrict__ outf, int A, int K, int cplx, long long lim)
{
    __shared__ float sH9[81];
    __shared__ float sRs[ENT];
    __shared__ float sRd[ENT];
    __shared__ float sT[ENT];
    __shared__ float sM[ENT];

    const int a = blockIdx.x;
    const int t = threadIdx.x;
    const int N = A * S18;
    const long long N2 = (long long)N * N;

    assemble_rotate(ons_feat + (size_t)a * PFEAT,
                    R + (size_t)a * ENT, R + (size_t)a * ENT,
                    sH9, sRs, sRd, sT, sM, t, 128);
    __syncthreads();

    for (int idx = t; idx < ENT; idx += 128) {
        const int i = idx / S18, j = idx - (idx / S18) * S18;
        const float v = sM[i * S18 + j] + sM[j * S18 + i];
        const long long I = (long long)a * S18 + i;
        const long long J = (long long)a * S18 + j;
        for (int k = 0; k < K; ++k) {
            const long long p1 = k * N2 + I * N + J;
            const long long off = cplx ? 2 * p1 : p1;
            if (off < lim) outf[off] += v;
        }
    }
}

extern "C" void kernel_launch(void* const* d_in, const int* in_sizes, int n_in,
                              void* d_out, int out_size, void* d_ws, size_t ws_size,
                              hipStream_t stream) {
    const float* hop_feat   = (const float*)d_in[0];
    const float* ons_feat   = (const float*)d_in[1];
    const float* R          = (const float*)d_in[2];
    const float* kpts       = (const float*)d_in[3];
    const float* shift      = (const float*)d_in[4];
    const int*   edge_index = (const int*)d_in[5];

    const int E = in_sizes[0] / PFEAT;   // 3072
    const int A = in_sizes[1] / PFEAT;   // 192
    const int K = in_sizes[3] / 3;       // 4

    const long long N  = (long long)A * S18;
    const long long n_real = (long long)K * N * N;
    const long long lim = (long long)out_size;
    const int cplx = (lim >= 2 * n_real) ? 1 : 0;

    float* outf = (float*)d_out;

    char* ws = (char*)d_ws;
    const size_t off_hop = 0;
    const size_t off_ons = off_hop + (size_t)E * ENT * 4;
    const size_t off_ent = off_ons + (size_t)A * ENT * 4;
    const size_t off_off = off_ent + (size_t)2 * E * 8;
    const size_t off_pc  = off_off + (size_t)(A + 2) * 4;
    const size_t off_ps  = off_pc  + (size_t)E * K * 4;
    const size_t base_need = off_ps + (size_t)E * K * 4;
    const size_t off_hT  = base_need;
    const size_t full_need = off_hT + (size_t)E * ENT * 4;

    if (ws_size >= base_need && A <= MAXA) {
        const int hasT = (ws_size >= full_need) ? 1 : 0;
        float* hop_rot  = (float*)(ws + off_hop);
        float* ons_rot  = (float*)(ws + off_ons);
        int2*  entries  = (int2*)(ws + off_ent);
        int*   offsets  = (int*)(ws + off_off);
        float* pcos     = (float*)(ws + off_pc);
        float* psin     = (float*)(ws + off_ps);
        float* hop_rotT = (float*)(ws + off_hT);

        prep_kernel<<<E + A + 1, 128, 0, stream>>>(
            hop_feat, ons_feat, R, edge_index, kpts, shift,
            hop_rot, hop_rotT, ons_rot, pcos, psin, offsets, entries,
            E, A, K, hasT);

        if (cplx == 0 && hasT && K <= 4) {
            const int nchunks = (int)((N + 255) / 256);
            dim3 grid((unsigned)nchunks, (unsigned)A);
            writer_colsK_kernel<<<grid, 256, 0, stream>>>(
                hop_rot, hop_rotT, ons_rot, offsets, entries, pcos,
                outf, A, K, lim);
        } else if (cplx == 0 && hasT) {
            const int nchunks = (int)((N + 383) / 384);
            dim3 grid((unsigned)nchunks, (unsigned)K, (unsigned)A);
            writer_cols_kernel<<<grid, 384, 0, stream>>>(
                hop_rot, hop_rotT, ons_rot, offsets, entries, pcos,
                outf, A, K, lim);
        } else {
            const size_t shmem = (size_t)(cplx ? 2 : 1) * N * sizeof(float);
            dim3 grid((unsigned)(A * 2), (unsigned)K);
            write_kernel<<<grid, 256, shmem, stream>>>(hop_rot, hop_rotT, ons_rot,
                                                       offsets, entries, pcos, psin,
                                                       outf, A, K, cplx, hasT, lim);
        }
    } else {
        const long long n4 = (lim + 3) / 4;
        const int zgrid = (int)((n4 + 255) / 256);
        zero_kernel<<<zgrid, 256, 0, stream>>>(outf, lim);
        edge_kernel<<<E, 256, 0, stream>>>(hop_feat, R, kpts, shift, edge_index,
                                           outf, E, A, K, cplx, lim);
        onsite_kernel<<<A, 128, 0, stream>>>(ons_feat, R, outf, A, K, cplx, lim);
    }
}

// Round 10
// 223.283 us; speedup vs baseline: 1.4144x; 1.4144x over previous
//
#include <hip/hip_runtime.h>

#define PFEAT 58
#define S18   18
#define ENT   324   // 18*18
#define MAXE  128   // max staged CSR entries per atom (avg degree ~32)
#define MAXA  256   // max atoms for in-prep CSR build

// p -> (row,col,factor) tables for _assemble (FLIST=[1,3,5], offs=[0,1,4])
__device__ __constant__ unsigned char c_row[PFEAT] = {
    0,0,0,0,0,0,0,0,0,
    1,1,1,2,2,2,3,3,3,
    1,1,1,1,1,2,2,2,2,2,3,3,3,3,3,
    4,4,4,4,4,5,5,5,5,5,6,6,6,6,6,7,7,7,7,7,8,8,8,8,8};
__device__ __constant__ unsigned char c_col[PFEAT] = {
    0,1,2,3,4,5,6,7,8,
    1,2,3,1,2,3,1,2,3,
    4,5,6,7,8,4,5,6,7,8,4,5,6,7,8,
    4,5,6,7,8,4,5,6,7,8,4,5,6,7,8,4,5,6,7,8,4,5,6,7,8};
__device__ __constant__ float c_fac[PFEAT] = {
    0.5f,1,1,1,1,1,1,1,1,
    0.5f,0.5f,0.5f,0.5f,0.5f,0.5f,0.5f,0.5f,0.5f,
    1,1,1,1,1,1,1,1,1,1,1,1,1,1,1,
    0.5f,0.5f,0.5f,0.5f,0.5f,0.5f,0.5f,0.5f,0.5f,0.5f,0.5f,0.5f,0.5f,
    0.5f,0.5f,0.5f,0.5f,0.5f,0.5f,0.5f,0.5f,0.5f,0.5f,0.5f,0.5f};

// int64-vs-int32 probe for edge_index (reference declares int64).
__device__ __forceinline__ bool detect_i64(const int* __restrict__ ei) {
    const uint2* p = (const uint2*)ei;
    unsigned acc = 0u;
#pragma unroll 8
    for (int m = 0; m < 64; ++m) acc |= p[m].y;
    return acc == 0u;
}

__device__ __forceinline__ int load_idx(const int* __restrict__ ei, int pos,
                                        bool is64, int A) {
    int v = is64 ? ei[2 * pos] : ei[pos];
    v = v < 0 ? 0 : (v >= A ? A - 1 : v);   // never fault on bad decode
    return v;
}

// Assemble 9x9 from feats, spin-double, rotate: sM = Rs * H18 * Rd^T.
__device__ __forceinline__ void assemble_rotate(
    const float* __restrict__ feat, const float* __restrict__ Rs,
    const float* __restrict__ Rd, float* sH9, float* sRs, float* sRd,
    float* sT, float* sM, int t, int nthreads)
{
    for (int idx = t; idx < ENT; idx += nthreads) { sRs[idx] = Rs[idx]; sRd[idx] = Rd[idx]; }
    if (t < 81) sH9[t] = 0.f;
    __syncthreads();
    if (t < PFEAT) sH9[c_row[t] * 9 + c_col[t]] = c_fac[t] * feat[t];
    __syncthreads();

    for (int idx = t; idx < ENT; idx += nthreads) {
        const int pp = idx / S18, q = idx - pp * S18;
        const int i = pp >> 1, u = pp & 1;
        float acc = 0.f;
#pragma unroll
        for (int j = 0; j < 9; ++j)
            acc += sH9[i * 9 + j] * sRd[q * S18 + 2 * j + u];
        sT[idx] = acc;
    }
    __syncthreads();

    for (int idx = t; idx < ENT; idx += nthreads) {
        const int p = idx / S18, q = idx - p * S18;
        float acc = 0.f;
#pragma unroll
        for (int pp = 0; pp < S18; ++pp)
            acc += sRs[p * S18 + pp] * sT[pp * S18 + q];
        sM[idx] = acc;
    }
}

// ---------------- CSR (write-once) path ----------------

// Block-specialized prep: blocks [0,E) edge rotate (+T, +phases);
// [E,E+A) onsite rotate; block E+A builds CSR. All independent.
__global__ __launch_bounds__(128) void prep_kernel(
    const float* __restrict__ hop_feat, const float* __restrict__ ons_feat,
    const float* __restrict__ R, const int* __restrict__ ei,
    const float* __restrict__ kpts, const float* __restrict__ shift,
    float* __restrict__ hop_rot, float* __restrict__ hop_rotT,
    float* __restrict__ ons_rot, float* __restrict__ pcos,
    float* __restrict__ psin, int* __restrict__ offsets,
    int2* __restrict__ entries, int E, int A, int K, int hasT)
{
    __shared__ float sH9[81];
    __shared__ float sRs[ENT];
    __shared__ float sRd[ENT];
    __shared__ float sT[ENT];
    __shared__ float sM[ENT];
    __shared__ int   scnt[MAXA];
    __shared__ int   scur[MAXA];
    __shared__ int   sflag;

    const int item = blockIdx.x;
    const int t = threadIdx.x;
    if (t == 0) sflag = detect_i64(ei) ? 1 : 0;
    __syncthreads();
    const bool s64 = sflag != 0;

    if (item == E + A) {
        // ---- CSR build ----
        for (int a = t; a < A; a += 128) scnt[a] = 0;
        __syncthreads();
        for (int e = t; e < E; e += 128) {
            const int a = load_idx(ei, e, s64, A);
            const int b = load_idx(ei, E + e, s64, A);
            atomicAdd(&scnt[a], 1);
            atomicAdd(&scnt[b], 1);
        }
        __syncthreads();
        if (t == 0) {
            int acc = 0;
            for (int a = 0; a < A; ++a) { scur[a] = acc; offsets[a] = acc; acc += scnt[a]; }
            offsets[A] = acc;
        }
        __syncthreads();
        for (int e = t; e < E; e += 128) {
            const int a = load_idx(ei, e, s64, A);
            const int b = load_idx(ei, E + e, s64, A);
            const int p = atomicAdd(&scur[a], 1);
            entries[p] = make_int2(e, b);                 // direct: row-atom a, col-block b
            const int q = atomicAdd(&scur[b], 1);
            entries[q] = make_int2(e | (1 << 30), a);     // conj:   row-atom b, col-block a
        }
        return;
    }

    const float* feat; const float* Rs; const float* Rd; float* outp;
    if (item < E) {
        const int a_s = load_idx(ei, item, s64, A);
        const int a_d = load_idx(ei, E + item, s64, A);
        feat = hop_feat + (size_t)item * PFEAT;
        Rs = R + (size_t)a_s * ENT;
        Rd = R + (size_t)a_d * ENT;
        outp = hop_rot + (size_t)item * ENT;
        for (int k = t; k < K; k += 128) {
            const float dot = kpts[k * 3 + 0] * shift[3 * item + 0]
                            + kpts[k * 3 + 1] * shift[3 * item + 1]
                            + kpts[k * 3 + 2] * shift[3 * item + 2];
            float sv, cv;
            sincosf(-6.28318530717958647692f * dot, &sv, &cv);
            pcos[item * K + k] = cv;
            psin[item * K + k] = sv;
        }
    } else {
        const int a = item - E;
        feat = ons_feat + (size_t)a * PFEAT;
        Rs = R + (size_t)a * ENT;
        Rd = Rs;
        outp = ons_rot + (size_t)a * ENT;
    }

    assemble_rotate(feat, Rs, Rd, sH9, sRs, sRd, sT, sM, t, 128);
    __syncthreads();

    for (int idx = t; idx < ENT; idx += 128) outp[idx] = sM[idx];
    if (item < E && hasT) {
        float* outpT = hop_rotT + (size_t)item * ENT;
        for (int idx = t; idx < ENT; idx += 128) {
            const int p = idx / S18, q = idx - p * S18;
            outpT[idx] = sM[q * S18 + p];   // T[p][q] = M[q][p]
        }
    }
}

// K-fused column-owner register writer, COMPILE-TIME K (full register
// promotion of acc[KK][18] — runtime-K version spilled to scratch, R9).
// One block per (col-chunk, atom-row a). Thread owns column c; each
// matching entry's 18-float gather is loaded once, FMA'd into KK planes.
template <int KK>
__global__ __launch_bounds__(256) void writer_colsK_kernel(
    const float* __restrict__ hop_rot,    // [E,324]
    const float* __restrict__ hop_rotT,   // [E,324]
    const float* __restrict__ ons_rot,    // [A,324]
    const int*   __restrict__ offsets,    // [A+1]
    const int2*  __restrict__ entries,    // [2E]
    const float* __restrict__ pcos,       // [E,KK]
    float* __restrict__ outf,
    int A, long long lim)
{
    __shared__ int   se[MAXE];
    __shared__ int   sb[MAXE];
    __shared__ float spc[MAXE][KK];
    __shared__ float sons[ENT];

    const int N = A * S18;
    const long long N2 = (long long)N * N;
    const int a = blockIdx.y;
    const int t = threadIdx.x;
    const int c = blockIdx.x * 256 + t;

    const int beg = offsets[a];
    const int cnt = offsets[a + 1] - beg;
    const int nst = cnt < MAXE ? cnt : MAXE;
    for (int n = t; n < nst; n += 256) {
        const int2 ent = entries[beg + n];
        se[n] = ent.x;
        sb[n] = ent.y;
        const int e0 = ent.x & 0x3FFFFFFF;
#pragma unroll
        for (int k = 0; k < KK; ++k) spc[n][k] = pcos[e0 * KK + k];
    }
    for (int idx = t; idx < ENT; idx += 256) sons[idx] = ons_rot[a * ENT + idx];
    __syncthreads();

    if (c >= N) return;
    const int b = c / S18, l = c - b * S18;

    float acc[KK][S18];
#pragma unroll
    for (int k = 0; k < KK; ++k)
#pragma unroll
        for (int i = 0; i < S18; ++i) acc[k][i] = 0.f;

    if (b == a) {
#pragma unroll
        for (int i = 0; i < S18; ++i) {
            const float v = sons[i * S18 + l] + sons[l * S18 + i];
#pragma unroll
            for (int k = 0; k < KK; ++k) acc[k][i] = v;
        }
    }

    for (int n = 0; n < nst; ++n) {
        if (sb[n] != b) continue;
        const int ex = se[n];
        const int e = ex & 0x3FFFFFFF;
        // direct: need col l of M (= row l of M^T); conj: need row l of M.
        const float* base = ((ex >> 30) & 1)
                          ? (hop_rot  + (size_t)e * ENT + l * S18)
                          : (hop_rotT + (size_t)e * ENT + l * S18);
        float v[S18];
#pragma unroll
        for (int i = 0; i < S18; ++i) v[i] = base[i];
#pragma unroll
        for (int k = 0; k < KK; ++k) {
            const float pc = spc[n][k];
#pragma unroll
            for (int i = 0; i < S18; ++i) acc[k][i] += v[i] * pc;
        }
    }
    for (int n = MAXE; n < cnt; ++n) {       // overflow path (rare)
        const int2 ent = entries[beg + n];
        if (ent.y != b) continue;
        const int e = ent.x & 0x3FFFFFFF;
        const float* base = ((ent.x >> 30) & 1)
                          ? (hop_rot  + (size_t)e * ENT + l * S18)
                          : (hop_rotT + (size_t)e * ENT + l * S18);
        float v[S18];
#pragma unroll
        for (int i = 0; i < S18; ++i) v[i] = base[i];
#pragma unroll
        for (int k = 0; k < KK; ++k) {
            const float pc = pcos[e * KK + k];
#pragma unroll
            for (int i = 0; i < S18; ++i) acc[k][i] += v[i] * pc;
        }
    }

    const long long colbase = (long long)a * S18 * N + c;
#pragma unroll
    for (int k = 0; k < KK; ++k) {
        const long long kb = (long long)k * N2 + colbase;
#pragma unroll
        for (int i = 0; i < S18; ++i) {
            const long long off = kb + (long long)i * N;
            if (off < lim) outf[off] = acc[k][i];
        }
    }
}

// Per-k column-owner writer (real mode, any K) — R8 version, fallback.
__global__ __launch_bounds__(384) void writer_cols_kernel(
    const float* __restrict__ hop_rot, const float* __restrict__ hop_rotT,
    const float* __restrict__ ons_rot, const int* __restrict__ offsets,
    const int2* __restrict__ entries, const float* __restrict__ pcos,
    float* __restrict__ outf, int A, int K, long long lim)
{
    __shared__ int   se[MAXE];
    __shared__ int   sb[MAXE];
    __shared__ float spc[MAXE];
    __shared__ float sons[ENT];

    const int N = A * S18;
    const int a = blockIdx.z;
    const int k = blockIdx.y;
    const int t = threadIdx.x;
    const int c = blockIdx.x * 384 + t;

    const int beg = offsets[a];
    const int cnt = offsets[a + 1] - beg;
    const int nst = cnt < MAXE ? cnt : MAXE;
    for (int n = t; n < nst; n += 384) {
        const int2 ent = entries[beg + n];
        se[n] = ent.x;
        sb[n] = ent.y;
        spc[n] = pcos[(ent.x & 0x3FFFFFFF) * K + k];
    }
    for (int idx = t; idx < ENT; idx += 384) sons[idx] = ons_rot[a * ENT + idx];
    __syncthreads();

    if (c >= N) return;
    const int b = c / S18, l = c - b * S18;

    float acc[S18];
    if (b == a) {
#pragma unroll
        for (int i = 0; i < S18; ++i)
            acc[i] = sons[i * S18 + l] + sons[l * S18 + i];
    } else {
#pragma unroll
        for (int i = 0; i < S18; ++i) acc[i] = 0.f;
    }

    for (int n = 0; n < nst; ++n) {
        if (sb[n] != b) continue;
        const int ex = se[n];
        const int e = ex & 0x3FFFFFFF;
        const float pc = spc[n];
        const float* base = ((ex >> 30) & 1)
                          ? (hop_rot  + (size_t)e * ENT + l * S18)
                          : (hop_rotT + (size_t)e * ENT + l * S18);
#pragma unroll
        for (int i = 0; i < S18; ++i) acc[i] += base[i] * pc;
    }
    for (int n = MAXE; n < cnt; ++n) {
        const int2 ent = entries[beg + n];
        if (ent.y != b) continue;
        const int e = ent.x & 0x3FFFFFFF;
        const float pc = pcos[e * K + k];
        const float* base = ((ent.x >> 30) & 1)
                          ? (hop_rot  + (size_t)e * ENT + l * S18)
                          : (hop_rotT + (size_t)e * ENT + l * S18);
#pragma unroll
        for (int i = 0; i < S18; ++i) acc[i] += base[i] * pc;
    }

    const long long rowbase = ((long long)k * N + (long long)a * S18) * (long long)N + c;
#pragma unroll
    for (int i = 0; i < S18; ++i) {
        const long long off = rowbase + (long long)i * N;
        if (off < lim) outf[off] = acc[i];
    }
}

// General writer (handles cplx) — LDS rowbuf version, fallback only.
__global__ __launch_bounds__(256) void write_kernel(
    const float* __restrict__ hop_rot, const float* __restrict__ hop_rotT,
    const float* __restrict__ ons_rot, const int* __restrict__ offsets,
    const int2* __restrict__ entries, const float* __restrict__ pcos,
    const float* __restrict__ psin, float* __restrict__ outf,
    int A, int K, int cplx, int hasT, long long lim)
{
    extern __shared__ float rowbuf[];     // (cplx?2:1)*N floats
    __shared__ int2  sent[MAXE];
    __shared__ float sphc[MAXE];
    __shared__ float sphs[MAXE];
    __shared__ float sons[ENT];

    const int N = A * S18;
    const int a    = blockIdx.x >> 1;
    const int half = blockIdx.x & 1;
    const int k = blockIdx.y;
    const int t = threadIdx.x;
    const int i0 = half * 9;
    const int stride = cplx ? 2 : 1;
    const int nbuf = stride * N;
    const int nbuf4 = nbuf >> 2;

    const int beg = offsets[a], end = offsets[a + 1];
    const int cnt = end - beg;
    const int nst = cnt < MAXE ? cnt : MAXE;
    for (int n = t; n < nst; n += 256) {
        const int2 ent = entries[beg + n];
        sent[n] = ent;
        const int e0 = ent.x & 0x3FFFFFFF;
        sphc[n] = pcos[e0 * K + k];
        if (cplx) sphs[n] = psin[e0 * K + k];
    }
    for (int idx = t; idx < ENT; idx += 256) sons[idx] = ons_rot[a * ENT + idx];
    __syncthreads();

    float4* rb4 = (float4*)rowbuf;
    const int total = cnt * S18;

    for (int ri = 0; ri < 9; ++ri) {
        const int i = i0 + ri;
        for (int idx = t; idx < nbuf4; idx += 256)
            rb4[idx] = make_float4(0.f, 0.f, 0.f, 0.f);
        __syncthreads();

        if (t < S18)
            atomicAdd(&rowbuf[stride * (a * S18 + t)],
                      sons[i * S18 + t] + sons[t * S18 + i]);

        for (int m = t; m < total; m += 256) {
            const int n = m / S18, l = m - n * S18;
            int2 ent; float pc, ps = 0.f;
            if (n < MAXE) {
                ent = sent[n]; pc = sphc[n]; if (cplx) ps = sphs[n];
            } else {
                ent = entries[beg + n];
                const int e0 = ent.x & 0x3FFFFFFF;
                pc = pcos[e0 * K + k]; if (cplx) ps = psin[e0 * K + k];
            }
            const int conjf = (ent.x >> 30) & 1;
            const int e = ent.x & 0x3FFFFFFF;
            const int b = ent.y;
            float v;
            if (!conjf)     v = hop_rot [(size_t)e * ENT + i * S18 + l];
            else if (hasT)  v = hop_rotT[(size_t)e * ENT + i * S18 + l];
            else            v = hop_rot [(size_t)e * ENT + l * S18 + i];
            atomicAdd(&rowbuf[stride * (b * S18 + l)], v * pc);
            if (cplx)
                atomicAdd(&rowbuf[stride * (b * S18 + l) + 1], conjf ? -v * ps : v * ps);
        }
        __syncthreads();

        const long long base = (long long)stride
                             * ((long long)k * N + (long long)a * S18 + i)
                             * (long long)N;
        float* dst = outf + base;
        if (base + nbuf <= lim && ((base & 3) == 0)) {
            float4* d4 = (float4*)dst;
            for (int idx = t; idx < nbuf4; idx += 256) d4[idx] = rb4[idx];
        } else {
            for (int idx = t; idx < nbuf; idx += 256)
                if (base + idx < lim) dst[idx] = rowbuf[idx];
        }
        __syncthreads();
    }
}

// ---------------- fallback (R3 atomic) path ----------------

__global__ __launch_bounds__(256) void zero_kernel(float* __restrict__ p, long long n)
{
    const long long i4 = ((long long)blockIdx.x * 256 + threadIdx.x) * 4;
    if (i4 + 3 < n) {
        *(float4*)(p + i4) = make_float4(0.f, 0.f, 0.f, 0.f);
    } else if (i4 < n) {
        for (long long i = i4; i < n; ++i) p[i] = 0.f;
    }
}

__global__ __launch_bounds__(256) void edge_kernel(
    const float* __restrict__ hop_feat, const float* __restrict__ R,
    const float* __restrict__ kpts, const float* __restrict__ shift,
    const int* __restrict__ edge_index, float* __restrict__ outf,
    int E, int A, int K, int cplx, long long lim)
{
    __shared__ float sH9[81];
    __shared__ float sRs[ENT];
    __shared__ float sRd[ENT];
    __shared__ float sT[ENT];
    __shared__ float sM[ENT];
    __shared__ float sC[8];
    __shared__ float sS[8];

    const int e = blockIdx.x;
    const int t = threadIdx.x;
    const int N = A * S18;
    const long long N2 = (long long)N * N;

    const bool is64 = detect_i64(edge_index);
    const int a = load_idx(edge_index, e, is64, A);
    const int b = load_idx(edge_index, E + e, is64, A);

    if (t < K && t < 8) {
        const float sx = shift[e * 3 + 0], sy = shift[e * 3 + 1], sz = shift[e * 3 + 2];
        const float dot = kpts[t * 3 + 0] * sx + kpts[t * 3 + 1] * sy + kpts[t * 3 + 2] * sz;
        float sv, cv;
        sincosf(-6.28318530717958647692f * dot, &sv, &cv);
        sC[t] = cv; sS[t] = sv;
    }

    assemble_rotate(hop_feat + (size_t)e * PFEAT,
                    R + (size_t)a * ENT, R + (size_t)b * ENT,
                    sH9, sRs, sRd, sT, sM, t, 256);
    __syncthreads();

    const int total = K * ENT;
    for (int idx = t; idx < total; idx += 256) {
        const int k = idx / ENT, r = idx - k * ENT;
        const int i = r / S18, j = r - i * S18;
        const float v = sM[r];
        const float re = v * sC[k];
        const float im = v * sS[k];
        const long long I = (long long)a * S18 + i;
        const long long J = (long long)b * S18 + j;
        const long long p1 = k * N2 + I * N + J;
        const long long p2 = k * N2 + J * N + I;
        if (cplx) {
            if (2 * p1 + 1 < lim) { atomicAdd(&outf[2 * p1], re); atomicAdd(&outf[2 * p1 + 1], im); }
            if (2 * p2 + 1 < lim) { atomicAdd(&outf[2 * p2], re); atomicAdd(&outf[2 * p2 + 1], -im); }
        } else {
            if (p1 < lim) atomicAdd(&outf[p1], re);
            if (p2 < lim) atomicAdd(&outf[p2], re);
        }
    }
}

__global__ __launch_bounds__(128) void onsite_kernel(
    const float* __restrict__ ons_feat, const float* __restrict__ R,
    float* __restrict__ outf, int A, int K, int cplx, long long lim)
{
    __shared__ float sH9[81];
    __shared__ float sRs[ENT];
    __shared__ float sRd[ENT];
    __shared__ float sT[ENT];
    __shared__ float sM[ENT];

    const int a = blockIdx.x;
    const int t = threadIdx.x;
    const int N = A * S18;
    const long long N2 = (long long)N * N;

    assemble_rotate(ons_feat + (size_t)a * PFEAT,
                    R + (size_t)a * ENT, R + (size_t)a * ENT,
                    sH9, sRs, sRd, sT, sM, t, 128);
    __syncthreads();

    for (int idx = t; idx < ENT; idx += 128) {
        const int i = idx / S18, j = idx - (idx / S18) * S18;
        const float v = sM[i * S18 + j] + sM[j * S18 + i];
        const long long I = (long long)a * S18 + i;
        const long long J = (long long)a * S18 + j;
        for (int k = 0; k < K; ++k) {
            const long long p1 = k * N2 + I * N + J;
            const long long off = cplx ? 2 * p1 : p1;
            if (off < lim) outf[off] += v;
        }
    }
}

extern "C" void kernel_launch(void* const* d_in, const int* in_sizes, int n_in,
                              void* d_out, int out_size, void* d_ws, size_t ws_size,
                              hipStream_t stream) {
    const float* hop_feat   = (const float*)d_in[0];
    const float* ons_feat   = (const float*)d_in[1];
    const float* R          = (const float*)d_in[2];
    const float* kpts       = (const float*)d_in[3];
    const float* shift      = (const float*)d_in[4];
    const int*   edge_index = (const int*)d_in[5];

    const int E = in_sizes[0] / PFEAT;   // 3072
    const int A = in_sizes[1] / PFEAT;   // 192
    const int K = in_sizes[3] / 3;       // 4

    const long long N  = (long long)A * S18;
    const long long n_real = (long long)K * N * N;
    const long long lim = (long long)out_size;
    const int cplx = (lim >= 2 * n_real) ? 1 : 0;

    float* outf = (float*)d_out;

    char* ws = (char*)d_ws;
    const size_t off_hop = 0;
    const size_t off_ons = off_hop + (size_t)E * ENT * 4;
    const size_t off_ent = off_ons + (size_t)A * ENT * 4;
    const size_t off_off = off_ent + (size_t)2 * E * 8;
    const size_t off_pc  = off_off + (size_t)(A + 2) * 4;
    const size_t off_ps  = off_pc  + (size_t)E * K * 4;
    const size_t base_need = off_ps + (size_t)E * K * 4;
    const size_t off_hT  = base_need;
    const size_t full_need = off_hT + (size_t)E * ENT * 4;

    if (ws_size >= base_need && A <= MAXA) {
        const int hasT = (ws_size >= full_need) ? 1 : 0;
        float* hop_rot  = (float*)(ws + off_hop);
        float* ons_rot  = (float*)(ws + off_ons);
        int2*  entries  = (int2*)(ws + off_ent);
        int*   offsets  = (int*)(ws + off_off);
        float* pcos     = (float*)(ws + off_pc);
        float* psin     = (float*)(ws + off_ps);
        float* hop_rotT = (float*)(ws + off_hT);

        prep_kernel<<<E + A + 1, 128, 0, stream>>>(
            hop_feat, ons_feat, R, edge_index, kpts, shift,
            hop_rot, hop_rotT, ons_rot, pcos, psin, offsets, entries,
            E, A, K, hasT);

        if (cplx == 0 && hasT && K >= 1 && K <= 4) {
            const int nchunks = (int)((N + 255) / 256);
            dim3 grid((unsigned)nchunks, (unsigned)A);
            switch (K) {
            case 1: writer_colsK_kernel<1><<<grid, 256, 0, stream>>>(
                        hop_rot, hop_rotT, ons_rot, offsets, entries, pcos, outf, A, lim); break;
            case 2: writer_colsK_kernel<2><<<grid, 256, 0, stream>>>(
                        hop_rot, hop_rotT, ons_rot, offsets, entries, pcos, outf, A, lim); break;
            case 3: writer_colsK_kernel<3><<<grid, 256, 0, stream>>>(
                        hop_rot, hop_rotT, ons_rot, offsets, entries, pcos, outf, A, lim); break;
            default: writer_colsK_kernel<4><<<grid, 256, 0, stream>>>(
                        hop_rot, hop_rotT, ons_rot, offsets, entries, pcos, outf, A, lim); break;
            }
        } else if (cplx == 0 && hasT) {
            const int nchunks = (int)((N + 383) / 384);
            dim3 grid((unsigned)nchunks, (unsigned)K, (unsigned)A);
            writer_cols_kernel<<<grid, 384, 0, stream>>>(
                hop_rot, hop_rotT, ons_rot, offsets, entries, pcos,
                outf, A, K, lim);
        } else {
            const size_t shmem = (size_t)(cplx ? 2 : 1) * N * sizeof(float);
            dim3 grid((unsigned)(A * 2), (unsigned)K);
            write_kernel<<<grid, 256, shmem, stream>>>(hop_rot, hop_rotT, ons_rot,
                                                       offsets, entries, pcos, psin,
                                                       outf, A, K, cplx, hasT, lim);
        }
    } else {
        const long long n4 = (lim + 3) / 4;
        const int zgrid = (int)((n4 + 255) / 256);
        zero_kernel<<<zgrid, 256, 0, stream>>>(outf, lim);
        edge_kernel<<<E, 256, 0, stream>>>(hop_feat, R, kpts, shift, edge_index,
                                           outf, E, A, K, cplx, lim);
        onsite_kernel<<<A, 128, 0, stream>>>(ons_feat, R, outf, A, K, cplx, lim);
    }
}